// Round 13
// baseline (1510.088 us; speedup 1.0000x reference)
//
#include <hip/hip_runtime.h>
#include <hip/hip_bf16.h>

#define NSEQ 512
#define SEGS 511     // L-1
#define CIN  32

typedef float v4f __attribute__((ext_vector_type(4)));

__device__ __forceinline__ float rl(float v, int lane) {
    return __int_as_float(__builtin_amdgcn_readlane(__float_as_int(v), lane));
}

__device__ __forceinline__ float tanhf_fast(float x) {
    // tanh(x) = sign(x) * (1 - e) / (1 + e),  e = exp(-2|x|)  — no overflow path
    float ax = fabsf(x);
    float e = __expf(-2.0f * ax);
#if __has_builtin(__builtin_amdgcn_rcpf)
    float r = (1.0f - e) * __builtin_amdgcn_rcpf(1.0f + e);
#else
    float r = (1.0f - e) / (1.0f + e);
#endif
    return copysignf(r, x);
}

// r13: r8 skeleton (2 waves/seq, col-split mm1, K-split mm2, 1 barrier/stage,
// weights register-resident via amdgpu_waves_per_eu(1,1) + opaque pins), with
// the BROADCAST TAX removed: instead of v_readlane+v_fmac (2 inst/MAC), the
// activation vectors (ys, X, h) are written to wave-local LDS and read back
// as same-address ds_read_b128 broadcasts (4 floats/inst, conflict-free).
//   mm1: 1 ds_write + 24 ds_read_b128 + 96 fma   (was 96 rl + 96 fma)
//   mm2: 1 ds_write + 16 ds_read_b128 + 64 fma   (was 64 rl + 64 fma)
// ~245 inst/wave/stage vs r8's ~350 — regime is per-wave ISSUE-bound
// (r9-r12 nulls: occupancy, vmcnt, SGPR batching, chain-shortening all flat).
// All new LDS traffic is WAVE-LOCAL: compiler lgkmcnt gives within-wave
// write->read visibility; no new barriers. Cross-wave z-exchange unchanged.
// Unlike r5 (weights via LDS, 1024B/read), broadcasts move 16B/inst -> LDS
// pipe load trivial. Summation order identical to r8 (absmax class 2-8).
__attribute__((amdgpu_waves_per_eu(1, 1)))
__global__ __launch_bounds__(128) void node_kernel(
    const float* __restrict__ cA, const float* __restrict__ cB,
    const float* __restrict__ cC, const float* __restrict__ cD,
    const int*   __restrict__ final_index,
    const float* __restrict__ W_init, const float* __restrict__ b_init,
    const float* __restrict__ W1, const float* __restrict__ b1,
    const float* __restrict__ W2, const float* __restrict__ b2,
    const float* __restrict__ W_out, const float* __restrict__ b_out,
    float* __restrict__ out)
{
    __shared__ __align__(16) float ysb[2][2][64];   // [parity][wave][m]  ys broadcast
    __shared__ __align__(16) float xvb[2][4][32];   // [wave][stage][i]   X broadcast
    __shared__ __align__(16) float hb [2][2][64];   // [parity][wave][j]  h broadcast
    __shared__ float zz[2][2][64];                  // [parity][wave][m]  mm2 partials

    const int tid  = threadIdx.x;
    const int lane = tid & 63;
    const int w    = tid >> 6;          // 0..1
    const int b    = blockIdx.x;
    const int ch   = lane & 31;
    const int col  = 64 * w + lane;     // this lane's h column (all distinct)

    // ---- W1 column in registers: w1c[i] = W1[i][col] ----
    float w1c[96];
#pragma unroll
    for (int i = 0; i < 96; ++i) w1c[i] = W1[i * 128 + col];
    // ---- W2 slice: w2c[j] = W2[64w+j][lane] ----
    float w2c[64];
#pragma unroll
    for (int j = 0; j < 64; ++j) w2c[j] = W2[(64 * w + j) * 64 + lane];
    float b1c = b1[col];
    float b2m = b2[lane];

    // pin: opaque -> cannot be rematerialized from memory inside the loop
#pragma unroll
    for (int i = 0; i < 96; ++i) asm volatile("" : "+v"(w1c[i]));
#pragma unroll
    for (int j = 0; j < 64; ++j) asm volatile("" : "+v"(w2c[j]));
    asm volatile("" : "+v"(b1c));
    asm volatile("" : "+v"(b2m));

    const float* a_ptr = cA + (size_t)b * SEGS * CIN;
    const float* bp    = cB + (size_t)b * SEGS * CIN;
    const float* cp    = cC + (size_t)b * SEGS * CIN;
    const float* dp    = cD + (size_t)b * SEGS * CIN;

    // ---- z0 = X(0) @ W_init + b_init  (replicated identically in both waves) ----
    float z = b_init[lane];
    {
        float a0 = a_ptr[ch];
#pragma unroll
        for (int i = 0; i < 32; ++i)
            z = fmaf(rl(a0, i), W_init[i * 64 + lane], z);
    }

    const int fi = final_index[b];

    // current-segment coeffs (lanes 0..31 meaningful; per-wave copy)
    float acur = a_ptr[ch], bcur = bp[ch], ccur = cp[ch], dcur = dp[ch];
    float k1 = 0.f, k2 = 0.f, k3 = 0.f, k4 = 0.f;

    __syncthreads();

// One RK stage. ys/X/h broadcast through wave-local LDS; same summation
// order as r8 (h0/h1 alternate even/odd, zp/zq alternate even/odd).
#define MM_STAGE(YSV, XS, PAR, KOUT) do {                                    \
    ysb[PAR][w][lane] = (YSV);                                               \
    float h0 = 0.f, h1 = 0.f;                                                \
    _Pragma("unroll")                                                        \
    for (int q = 0; q < 16; ++q) {                                           \
        v4f u = *reinterpret_cast<const v4f*>(&ysb[PAR][w][4 * q]);          \
        h0 = fmaf(u.x, w1c[4 * q],     h0);                                  \
        h1 = fmaf(u.y, w1c[4 * q + 1], h1);                                  \
        h0 = fmaf(u.z, w1c[4 * q + 2], h0);                                  \
        h1 = fmaf(u.w, w1c[4 * q + 3], h1);                                  \
    }                                                                        \
    _Pragma("unroll")                                                        \
    for (int q = 0; q < 8; ++q) {                                            \
        v4f u = *reinterpret_cast<const v4f*>(&xvb[w][XS][4 * q]);           \
        h0 = fmaf(u.x, w1c[64 + 4 * q],     h0);                             \
        h1 = fmaf(u.y, w1c[64 + 4 * q + 1], h1);                             \
        h0 = fmaf(u.z, w1c[64 + 4 * q + 2], h0);                             \
        h1 = fmaf(u.w, w1c[64 + 4 * q + 3], h1);                             \
    }                                                                        \
    float h = tanhf_fast(h0 + h1 + b1c);  /* this lane's col = 64w+lane */   \
    hb[PAR][w][lane] = h;                                                    \
    float zp = 0.f, zq = 0.f;                                                \
    _Pragma("unroll")                                                        \
    for (int q = 0; q < 16; ++q) {                                           \
        v4f hv = *reinterpret_cast<const v4f*>(&hb[PAR][w][4 * q]);          \
        zp = fmaf(hv.x, w2c[4 * q],     zp);                                 \
        zq = fmaf(hv.y, w2c[4 * q + 1], zq);                                 \
        zp = fmaf(hv.z, w2c[4 * q + 2], zp);                                 \
        zq = fmaf(hv.w, w2c[4 * q + 3], zq);                                 \
    }                                                                        \
    zz[PAR][w][lane] = zp + zq;                                              \
    __syncthreads();                                                         \
    float zo = zz[PAR][w ^ 1][lane];                                         \
    KOUT = tanhf_fast(zp + zq + zo + b2m);                                   \
} while (0)

    for (int t = 0; t < fi; ++t) {
        // ---- step-top, k-independent: spline points + X staging ----
        float i13 = fmaf(dcur, 1.0f / 9.0f, 0.5f * ccur);
        float x13 = fmaf(fmaf(i13, 1.0f / 3.0f, bcur), 1.0f / 3.0f, acur);
        float i23 = fmaf(dcur, 2.0f / 9.0f, 0.5f * ccur);
        float x23 = fmaf(fmaf(i23, 2.0f / 3.0f, bcur), 2.0f / 3.0f, acur);
        float xbl = acur + (bcur + (0.5f * ccur + dcur * (1.0f / 3.0f)));
        // lanes m and m+32 write the same value to the same address (benign)
        xvb[w][0][ch] = acur;
        xvb[w][1][ch] = x13;
        xvb[w][2][ch] = x23;

        // next-segment prefetch (xb consumer sits after stage 1)
        const int tn  = (t + 1 < SEGS) ? (t + 1) : (SEGS - 1);
        const int off = tn * CIN + ch;
        float anx = a_ptr[off];
        float bnx = bp[off];
        float cnx = cp[off];
        float dnx = dp[off];

        // ---- RK4 3/8-rule, dt = 1 ----
        MM_STAGE(z, 0, 0, k1);
        // stage-4 X written here: ~2 stages of cover for the anx vmcnt wait
        float xb = (t < SEGS - 1) ? anx : xbl;
        xvb[w][3][ch] = xb;
        float ys1 = fmaf(k1, 1.0f / 3.0f, z);
        MM_STAGE(ys1, 1, 1, k2);
        float ys2 = z + (k2 - k1 * (1.0f / 3.0f));
        MM_STAGE(ys2, 2, 0, k3);
        float ys3 = z + (k1 - k2 + k3);
        MM_STAGE(ys3, 3, 1, k4);

        z += (k1 + 3.0f * (k2 + k3) + k4) * 0.125f;
        acur = anx; bcur = bnx; ccur = cnx; dcur = dnx;
    }

    // ---- out[b] = z_fi @ W_out + b_out ----
    if (w == 0 && lane < 10) {
        float acc = b_out[lane];
#pragma unroll
        for (int m = 0; m < 64; ++m)
            acc = fmaf(rl(z, m), W_out[m * 10 + lane], acc);
        out[b * 10 + lane] = acc;
    }
}

extern "C" void kernel_launch(void* const* d_in, const int* in_sizes, int n_in,
                              void* d_out, int out_size, void* d_ws, size_t ws_size,
                              hipStream_t stream) {
    const float* cA     = (const float*)d_in[1];
    const float* cBc    = (const float*)d_in[2];
    const float* cCc    = (const float*)d_in[3];
    const float* cDc    = (const float*)d_in[4];
    const int*   fidx   = (const int*)d_in[5];
    const float* W_init = (const float*)d_in[6];
    const float* b_init = (const float*)d_in[7];
    const float* W1     = (const float*)d_in[8];
    const float* b1     = (const float*)d_in[9];
    const float* W2     = (const float*)d_in[10];
    const float* b2     = (const float*)d_in[11];
    const float* W_out  = (const float*)d_in[12];
    const float* b_out  = (const float*)d_in[13];

    node_kernel<<<dim3(NSEQ), dim3(128), 0, stream>>>(
        cA, cBc, cCc, cDc, fidx, W_init, b_init, W1, b1, W2, b2, W_out, b_out,
        (float*)d_out);
}

// Round 14
// 1373.299 us; speedup vs baseline: 1.0996x; 1.0996x over previous
//
#include <hip/hip_runtime.h>
#include <hip/hip_bf16.h>

#define NSEQ 512
#define SEGS 511     // L-1
#define CIN  32

typedef float v2f __attribute__((ext_vector_type(2)));
typedef float v4f __attribute__((ext_vector_type(4)));

__device__ __forceinline__ float rl(float v, int lane) {
    return __int_as_float(__builtin_amdgcn_readlane(__float_as_int(v), lane));
}

__device__ __forceinline__ float tanhf_fast(float x) {
    // tanh(x) = sign(x) * (1 - e) / (1 + e),  e = exp(-2|x|)  — no overflow path
    float ax = fabsf(x);
    float e = __expf(-2.0f * ax);
#if __has_builtin(__builtin_amdgcn_rcpf)
    float r = (1.0f - e) * __builtin_amdgcn_rcpf(1.0f + e);
#else
    float r = (1.0f - e) / (1.0f + e);
#endif
    return copysignf(r, x);
}

// packed fp32 fma: acc.x += a.x*b.x; acc.y += a.y*b.y  (two IEEE fmas).
// All-VGPR operands — legal VOP3P on gfx950 (r3's failure was an SGPR src).
__device__ __forceinline__ void pkfma(v2f& acc, v2f a, v2f b) {
    asm("v_pk_fma_f32 %0, %1, %2, %0" : "+v"(acc) : "v"(a), "v"(b));
}

// r14: r13 skeleton (2 waves/seq, col-split mm1, K-split mm2, 1 barrier/stage,
// LDS same-address broadcast of activations, weights register-resident via
// amdgpu_waves_per_eu(1,1) + opaque pins) with v_pk_fma_f32:
//   mm1: 24 ds_read_b128 + 48 pk_fma (was 96 fma), 2 chains -> latency ~96
//   mm2: 16 ds_read_b128 + 32 pk_fma (was 64 fma), 2 chains -> latency ~64
// r13's lesson: wall = max(issue, chain latency); pk_fma cuts BOTH.
__attribute__((amdgpu_waves_per_eu(1, 1)))
__global__ __launch_bounds__(128) void node_kernel(
    const float* __restrict__ cA, const float* __restrict__ cB,
    const float* __restrict__ cC, const float* __restrict__ cD,
    const int*   __restrict__ final_index,
    const float* __restrict__ W_init, const float* __restrict__ b_init,
    const float* __restrict__ W1, const float* __restrict__ b1,
    const float* __restrict__ W2, const float* __restrict__ b2,
    const float* __restrict__ W_out, const float* __restrict__ b_out,
    float* __restrict__ out)
{
    __shared__ __align__(16) float ysb[2][2][64];   // [parity][wave][m]  ys broadcast
    __shared__ __align__(16) float xvb[2][4][32];   // [wave][stage][i]   X broadcast
    __shared__ __align__(16) float hb [2][2][64];   // [parity][wave][j]  h broadcast
    __shared__ float zz[2][2][64];                  // [parity][wave][m]  mm2 partials

    const int tid  = threadIdx.x;
    const int lane = tid & 63;
    const int w    = tid >> 6;          // 0..1
    const int b    = blockIdx.x;
    const int ch   = lane & 31;
    const int col  = 64 * w + lane;     // this lane's h column (all distinct)

    // ---- W1 column as row-pairs: w1p[i] = (W1[2i][col], W1[2i+1][col]) ----
    v2f w1p[48];
#pragma unroll
    for (int i = 0; i < 48; ++i) {
        w1p[i].x = W1[(2 * i) * 128 + col];
        w1p[i].y = W1[(2 * i + 1) * 128 + col];
    }
    // ---- W2 slice as row-pairs: w2p[i] = (W2[64w+2i][lane], W2[64w+2i+1][lane]) ----
    v2f w2p[32];
#pragma unroll
    for (int i = 0; i < 32; ++i) {
        w2p[i].x = W2[(64 * w + 2 * i) * 64 + lane];
        w2p[i].y = W2[(64 * w + 2 * i + 1) * 64 + lane];
    }
    float b1c = b1[col];
    float b2m = b2[lane];

    // pin: opaque -> cannot be rematerialized from memory inside the loop
#pragma unroll
    for (int i = 0; i < 48; ++i) asm volatile("" : "+v"(w1p[i]));
#pragma unroll
    for (int i = 0; i < 32; ++i) asm volatile("" : "+v"(w2p[i]));
    asm volatile("" : "+v"(b1c));
    asm volatile("" : "+v"(b2m));

    const float* a_ptr = cA + (size_t)b * SEGS * CIN;
    const float* bp    = cB + (size_t)b * SEGS * CIN;
    const float* cp    = cC + (size_t)b * SEGS * CIN;
    const float* dp    = cD + (size_t)b * SEGS * CIN;

    // ---- z0 = X(0) @ W_init + b_init  (replicated identically in both waves) ----
    float z = b_init[lane];
    {
        float a0 = a_ptr[ch];
#pragma unroll
        for (int i = 0; i < 32; ++i)
            z = fmaf(rl(a0, i), W_init[i * 64 + lane], z);
    }

    const int fi = final_index[b];

    // current-segment coeffs (lanes 0..31 meaningful; per-wave copy)
    float acur = a_ptr[ch], bcur = bp[ch], ccur = cp[ch], dcur = dp[ch];
    float k1 = 0.f, k2 = 0.f, k3 = 0.f, k4 = 0.f;

    __syncthreads();

// One RK stage: LDS-broadcast activations + packed fma.
// accA covers even row-pairs of each quad, accB the odd pairs (2 indep chains).
#define MM_STAGE(YSV, XS, PAR, KOUT) do {                                    \
    ysb[PAR][w][lane] = (YSV);                                               \
    v2f accA = {0.f, 0.f}, accB = {0.f, 0.f};                                \
    _Pragma("unroll")                                                        \
    for (int q = 0; q < 16; ++q) {                                           \
        v4f u = *reinterpret_cast<const v4f*>(&ysb[PAR][w][4 * q]);          \
        v2f u01 = __builtin_shufflevector(u, u, 0, 1);                       \
        v2f u23 = __builtin_shufflevector(u, u, 2, 3);                       \
        pkfma(accA, u01, w1p[2 * q]);                                        \
        pkfma(accB, u23, w1p[2 * q + 1]);                                    \
    }                                                                        \
    _Pragma("unroll")                                                        \
    for (int q = 0; q < 8; ++q) {                                            \
        v4f u = *reinterpret_cast<const v4f*>(&xvb[w][XS][4 * q]);           \
        v2f u01 = __builtin_shufflevector(u, u, 0, 1);                       \
        v2f u23 = __builtin_shufflevector(u, u, 2, 3);                       \
        pkfma(accA, u01, w1p[32 + 2 * q]);                                   \
        pkfma(accB, u23, w1p[33 + 2 * q]);                                   \
    }                                                                        \
    float h = tanhf_fast((accA.x + accB.x) + (accA.y + accB.y) + b1c);       \
    hb[PAR][w][lane] = h;                                                    \
    v2f za = {0.f, 0.f}, zb = {0.f, 0.f};                                    \
    _Pragma("unroll")                                                        \
    for (int q = 0; q < 16; ++q) {                                           \
        v4f hv = *reinterpret_cast<const v4f*>(&hb[PAR][w][4 * q]);          \
        v2f h01 = __builtin_shufflevector(hv, hv, 0, 1);                     \
        v2f h23 = __builtin_shufflevector(hv, hv, 2, 3);                     \
        pkfma(za, h01, w2p[2 * q]);                                          \
        pkfma(zb, h23, w2p[2 * q + 1]);                                      \
    }                                                                        \
    float zw = (za.x + zb.x) + (za.y + zb.y);                                \
    zz[PAR][w][lane] = zw;                                                   \
    __syncthreads();                                                         \
    float zo = zz[PAR][w ^ 1][lane];                                         \
    KOUT = tanhf_fast(zw + zo + b2m);                                        \
} while (0)

    for (int t = 0; t < fi; ++t) {
        // ---- step-top, k-independent: spline points + X staging ----
        float i13 = fmaf(dcur, 1.0f / 9.0f, 0.5f * ccur);
        float x13 = fmaf(fmaf(i13, 1.0f / 3.0f, bcur), 1.0f / 3.0f, acur);
        float i23 = fmaf(dcur, 2.0f / 9.0f, 0.5f * ccur);
        float x23 = fmaf(fmaf(i23, 2.0f / 3.0f, bcur), 2.0f / 3.0f, acur);
        float xbl = acur + (bcur + (0.5f * ccur + dcur * (1.0f / 3.0f)));
        // lanes m and m+32 write the same value to the same address (benign)
        xvb[w][0][ch] = acur;
        xvb[w][1][ch] = x13;
        xvb[w][2][ch] = x23;

        // next-segment prefetch (xb consumer sits after stage 1)
        const int tn  = (t + 1 < SEGS) ? (t + 1) : (SEGS - 1);
        const int off = tn * CIN + ch;
        float anx = a_ptr[off];
        float bnx = bp[off];
        float cnx = cp[off];
        float dnx = dp[off];

        // ---- RK4 3/8-rule, dt = 1 ----
        MM_STAGE(z, 0, 0, k1);
        // stage-4 X written here: ~2 stages of cover for the anx vmcnt wait
        float xb = (t < SEGS - 1) ? anx : xbl;
        xvb[w][3][ch] = xb;
        float ys1 = fmaf(k1, 1.0f / 3.0f, z);
        MM_STAGE(ys1, 1, 1, k2);
        float ys2 = z + (k2 - k1 * (1.0f / 3.0f));
        MM_STAGE(ys2, 2, 0, k3);
        float ys3 = z + (k1 - k2 + k3);
        MM_STAGE(ys3, 3, 1, k4);

        z += (k1 + 3.0f * (k2 + k3) + k4) * 0.125f;
        acur = anx; bcur = bnx; ccur = cnx; dcur = dnx;
    }

    // ---- out[b] = z_fi @ W_out + b_out ----
    if (w == 0 && lane < 10) {
        float acc = b_out[lane];
#pragma unroll
        for (int m = 0; m < 64; ++m)
            acc = fmaf(rl(z, m), W_out[m * 10 + lane], acc);
        out[b * 10 + lane] = acc;
    }
}

extern "C" void kernel_launch(void* const* d_in, const int* in_sizes, int n_in,
                              void* d_out, int out_size, void* d_ws, size_t ws_size,
                              hipStream_t stream) {
    const float* cA     = (const float*)d_in[1];
    const float* cBc    = (const float*)d_in[2];
    const float* cCc    = (const float*)d_in[3];
    const float* cDc    = (const float*)d_in[4];
    const int*   fidx   = (const int*)d_in[5];
    const float* W_init = (const float*)d_in[6];
    const float* b_init = (const float*)d_in[7];
    const float* W1     = (const float*)d_in[8];
    const float* b1     = (const float*)d_in[9];
    const float* W2     = (const float*)d_in[10];
    const float* b2     = (const float*)d_in[11];
    const float* W_out  = (const float*)d_in[12];
    const float* b_out  = (const float*)d_in[13];

    node_kernel<<<dim3(NSEQ), dim3(128), 0, stream>>>(
        cA, cBc, cCc, cDc, fidx, W_init, b_init, W1, b1, W2, b2, W_out, b_out,
        (float*)d_out);
}

// Round 16
// 1369.743 us; speedup vs baseline: 1.1025x; 1.0026x over previous
//
#include <hip/hip_runtime.h>
#include <hip/hip_bf16.h>

#define NSEQ 512
#define SEGS 511     // L-1
#define CIN  32

typedef float v2f __attribute__((ext_vector_type(2)));
typedef float v4f __attribute__((ext_vector_type(4)));

__device__ __forceinline__ float rl(float v, int lane) {
    return __int_as_float(__builtin_amdgcn_readlane(__float_as_int(v), lane));
}

__device__ __forceinline__ float tanhf_fast(float x) {
    float ax = fabsf(x);
    float e = __expf(-2.0f * ax);
#if __has_builtin(__builtin_amdgcn_rcpf)
    float r = (1.0f - e) * __builtin_amdgcn_rcpf(1.0f + e);
#else
    float r = (1.0f - e) / (1.0f + e);
#endif
    return copysignf(r, x);
}

// packed fp32 fma: acc.x += a.x*b.x; acc.y += a.y*b.y (two IEEE fmas).
// NOTE: inputs must be plain "v" (r15's "+v" in the input list = ill-formed).
__device__ __forceinline__ void pkfma(v2f& acc, v2f a, v2f b) {
    asm("v_pk_fma_f32 %0, %1, %2, %0" : "+v"(acc) : "v"(a), "v"(b));
}

// r16 = r15 with the asm constraint fixed.
// Design: r12's mm1 LINEARITY DECOMPOSITION x r14's LDS-broadcast+pk_fma.
// Regime (r8/r13/r14 all ~1400 us at VALUBusy 34/18/14%): wall = straggler's
// SERIAL CHAIN (2044 stages x ~1600 cyc); issue count irrelevant.
// Decomposition pulls the 96-wide mm1 dot OFF the chain:
//   mm1(ys_s)[col] = Zs[col] + XP_s[col] + combo_s(K1,K2,K3)[col]
//   Zs: z-dot, once per STEP (z-broadcast trip amortized; XP dots fill it)
//   XP_s: spline dots, k-independent (step-top, off-chain)
//   K_n: 64-wide k-dot -- the only per-stage chain dot; stage 4 needs none.
// Per-stage chain: tanh -> k-trip+32pkfma -> tanh -> h-trip -> mm2 32pkfma
// -> zz+barrier trip  ~= 750-900 cyc vs r14's ~1600.
__attribute__((amdgpu_waves_per_eu(1, 1)))
__global__ __launch_bounds__(128) void node_kernel(
    const float* __restrict__ cA, const float* __restrict__ cB,
    const float* __restrict__ cC, const float* __restrict__ cD,
    const int*   __restrict__ final_index,
    const float* __restrict__ W_init, const float* __restrict__ b_init,
    const float* __restrict__ W1, const float* __restrict__ b1,
    const float* __restrict__ W2, const float* __restrict__ b2,
    const float* __restrict__ W_out, const float* __restrict__ b_out,
    float* __restrict__ out)
{
    __shared__ __align__(16) float zbc [2][64];      // [wave][i]   z broadcast (per step)
    __shared__ __align__(16) float xvb [2][4][32];   // [wave][s][i] X broadcast
    __shared__ __align__(16) float kbc [2][2][64];   // [wave][par][i] k broadcast
    __shared__ __align__(16) float hbuf[2][2][64];   // [wave][par][j] h broadcast
    __shared__ float zz[2][2][64];                   // [par][wave][m] mm2 partials

    const int tid  = threadIdx.x;
    const int lane = tid & 63;
    const int w    = tid >> 6;          // 0..1
    const int b    = blockIdx.x;
    const int ch   = lane & 31;
    const int col  = 64 * w + lane;     // this lane's h column

    // ---- weights in registers (paired for pk_fma) ----
    v2f w1z[32];   // (W1[2i][col], W1[2i+1][col])      rows 0..63  (z part)
#pragma unroll
    for (int i = 0; i < 32; ++i) {
        w1z[i].x = W1[(2 * i) * 128 + col];
        w1z[i].y = W1[(2 * i + 1) * 128 + col];
    }
    v2f w1x[16];   // (W1[64+2i][col], W1[64+2i+1][col]) rows 64..95 (X part)
#pragma unroll
    for (int i = 0; i < 16; ++i) {
        w1x[i].x = W1[(64 + 2 * i) * 128 + col];
        w1x[i].y = W1[(65 + 2 * i) * 128 + col];
    }
    v2f w2p[32];   // (W2[64w+2i][lane], W2[64w+2i+1][lane])
#pragma unroll
    for (int i = 0; i < 32; ++i) {
        w2p[i].x = W2[(64 * w + 2 * i) * 64 + lane];
        w2p[i].y = W2[(64 * w + 2 * i + 1) * 64 + lane];
    }
    float b1c = b1[col];
    float b2m = b2[lane];

    // pin against loop-remat
#pragma unroll
    for (int i = 0; i < 32; ++i) asm volatile("" : "+v"(w1z[i]));
#pragma unroll
    for (int i = 0; i < 16; ++i) asm volatile("" : "+v"(w1x[i]));
#pragma unroll
    for (int i = 0; i < 32; ++i) asm volatile("" : "+v"(w2p[i]));
    asm volatile("" : "+v"(b1c));
    asm volatile("" : "+v"(b2m));

    const float* a_ptr = cA + (size_t)b * SEGS * CIN;
    const float* bp    = cB + (size_t)b * SEGS * CIN;
    const float* cp    = cC + (size_t)b * SEGS * CIN;
    const float* dp    = cD + (size_t)b * SEGS * CIN;

    // ---- z0 = X(0) @ W_init + b_init ----
    float z = b_init[lane];
    {
        float a0 = a_ptr[ch];
#pragma unroll
        for (int i = 0; i < 32; ++i)
            z = fmaf(rl(a0, i), W_init[i * 64 + lane], z);
    }

    const int fi = final_index[b];

    float acur = a_ptr[ch], bcur = bp[ch], ccur = cp[ch], dcur = dp[ch];

    __syncthreads();

// 64-wide dot of LDS-broadcast vector BUF against paired weights WP -> OUT
#define DOT64(BUF, WP, OUT) do {                                             \
    v2f dA = {0.f, 0.f}, dB = {0.f, 0.f};                                    \
    _Pragma("unroll")                                                        \
    for (int q = 0; q < 16; ++q) {                                           \
        v4f u = *reinterpret_cast<const v4f*>(&(BUF)[4 * q]);                \
        v2f u01 = __builtin_shufflevector(u, u, 0, 1);                       \
        v2f u23 = __builtin_shufflevector(u, u, 2, 3);                       \
        pkfma(dA, u01, (WP)[2 * q]);                                         \
        pkfma(dB, u23, (WP)[2 * q + 1]);                                     \
    }                                                                        \
    OUT = (dA.x + dB.x) + (dA.y + dB.y);                                     \
} while (0)

// 32-wide dot (X part)
#define DOT32(BUF, WP, OUT) do {                                             \
    v2f dA = {0.f, 0.f}, dB = {0.f, 0.f};                                    \
    _Pragma("unroll")                                                        \
    for (int q = 0; q < 8; ++q) {                                            \
        v4f u = *reinterpret_cast<const v4f*>(&(BUF)[4 * q]);                \
        v2f u01 = __builtin_shufflevector(u, u, 0, 1);                       \
        v2f u23 = __builtin_shufflevector(u, u, 2, 3);                       \
        pkfma(dA, u01, (WP)[2 * q]);                                         \
        pkfma(dB, u23, (WP)[2 * q + 1]);                                     \
    }                                                                        \
    OUT = (dA.x + dB.x) + (dA.y + dB.y);                                     \
} while (0)

// one RK stage: h from precomputed arg; mm2; exchange; k. PAR alternates.
#define STAGE(ARG, PAR, KOUT) do {                                           \
    float h = tanhf_fast(ARG);                                               \
    hbuf[w][PAR][lane] = h;                                                  \
    v2f za = {0.f, 0.f}, zb2 = {0.f, 0.f};                                   \
    _Pragma("unroll")                                                        \
    for (int q = 0; q < 16; ++q) {                                           \
        v4f hv = *reinterpret_cast<const v4f*>(&hbuf[w][PAR][4 * q]);        \
        v2f h01 = __builtin_shufflevector(hv, hv, 0, 1);                     \
        v2f h23 = __builtin_shufflevector(hv, hv, 2, 3);                     \
        pkfma(za, h01, w2p[2 * q]);                                          \
        pkfma(zb2, h23, w2p[2 * q + 1]);                                     \
    }                                                                        \
    float zw = (za.x + zb2.x) + (za.y + zb2.y);                              \
    zz[PAR][w][lane] = zw;                                                   \
    __syncthreads();                                                         \
    float z3 = zw + zz[PAR][w ^ 1][lane] + b2m;                              \
    KOUT = tanhf_fast(z3);                                                   \
} while (0)

    for (int t = 0; t < fi; ++t) {
        // ---- step top (k-independent; fills the z-trip latency) ----
        zbc[w][lane] = z;                         // z broadcast for Z-dot
        float i13 = fmaf(dcur, 1.0f / 9.0f, 0.5f * ccur);
        float x13 = fmaf(fmaf(i13, 1.0f / 3.0f, bcur), 1.0f / 3.0f, acur);
        float i23 = fmaf(dcur, 2.0f / 9.0f, 0.5f * ccur);
        float x23 = fmaf(fmaf(i23, 2.0f / 3.0f, bcur), 2.0f / 3.0f, acur);
        float xbl = acur + (bcur + (0.5f * ccur + dcur * (1.0f / 3.0f)));
        xvb[w][0][ch] = acur;                     // duplicate lane writes benign
        xvb[w][1][ch] = x13;
        xvb[w][2][ch] = x23;

        const int tn  = (t + 1 < SEGS) ? (t + 1) : (SEGS - 1);
        const int off = tn * CIN + ch;
        float anx = a_ptr[off];
        float bnx = bp[off];
        float cnx = cp[off];
        float dnx = dp[off];

        float Zs;
        DOT64(zbc[w], w1z, Zs);
        Zs += b1c;
        float XP0, XP1, XP2;
        DOT32(xvb[w][0], w1x, XP0);
        DOT32(xvb[w][1], w1x, XP1);
        DOT32(xvb[w][2], w1x, XP2);
        float hb0 = Zs + XP0, hb1 = Zs + XP1, hb2 = Zs + XP2;

        // ---- stage 1: arg = Zs + XP0 (no K) ----
        float k1;
        STAGE(hb0, 0, k1);
        kbc[w][0][lane] = k1;

        // stage-4 spline point now (prefetch cover ~2 stages)
        float xb = (t < SEGS - 1) ? anx : xbl;
        xvb[w][3][ch] = xb;
        float XP3;
        DOT32(xvb[w][3], w1x, XP3);
        float hb3 = Zs + XP3;

        float K1;
        DOT64(kbc[w][0], w1z, K1);

        // ---- stage 2: arg = hb1 + K1/3 ----
        float k2;
        STAGE(fmaf(K1, 1.0f / 3.0f, hb1), 1, k2);
        kbc[w][1][lane] = k2;
        float K2;
        DOT64(kbc[w][1], w1z, K2);

        // ---- stage 3: arg = hb2 + (K2 - K1/3) ----
        float k3;
        STAGE(hb2 + (K2 - K1 * (1.0f / 3.0f)), 0, k3);
        kbc[w][0][lane] = k3;
        float K3;
        DOT64(kbc[w][0], w1z, K3);

        // ---- stage 4: arg = hb3 + (K1 - K2 + K3); no K4 needed ----
        float k4;
        STAGE(hb3 + ((K1 - K2) + K3), 1, k4);

        z += (k1 + 3.0f * (k2 + k3) + k4) * 0.125f;
        acur = anx; bcur = bnx; ccur = cnx; dcur = dnx;
    }

    // ---- out[b] = z_fi @ W_out + b_out ----
    if (w == 0 && lane < 10) {
        float acc = b_out[lane];
#pragma unroll
        for (int m = 0; m < 64; ++m)
            acc = fmaf(rl(z, m), W_out[m * 10 + lane], acc);
        out[b * 10 + lane] = acc;
    }
}

extern "C" void kernel_launch(void* const* d_in, const int* in_sizes, int n_in,
                              void* d_out, int out_size, void* d_ws, size_t ws_size,
                              hipStream_t stream) {
    const float* cA     = (const float*)d_in[1];
    const float* cBc    = (const float*)d_in[2];
    const float* cCc    = (const float*)d_in[3];
    const float* cDc    = (const float*)d_in[4];
    const int*   fidx   = (const int*)d_in[5];
    const float* W_init = (const float*)d_in[6];
    const float* b_init = (const float*)d_in[7];
    const float* W1     = (const float*)d_in[8];
    const float* b1     = (const float*)d_in[9];
    const float* W2     = (const float*)d_in[10];
    const float* b2     = (const float*)d_in[11];
    const float* W_out  = (const float*)d_in[12];
    const float* b_out  = (const float*)d_in[13];

    node_kernel<<<dim3(NSEQ), dim3(128), 0, stream>>>(
        cA, cBc, cCc, cDc, fidx, W_init, b_init, W1, b1, W2, b2, W_out, b_out,
        (float*)d_out);
}